// Round 9
// baseline (114.949 us; speedup 1.0000x reference)
//
#include <hip/hip_runtime.h>

// Bahdanau additive attention: B=8, TE=512, TD=256, H=256, fp32.
//   We = enc @ W_a; Uh = dec @ U_a
//   e[b,j,i] = softmax_i( sum_h V[h]*tanh(We[b,i,h]+Uh[b,j,h]) )
//   c[b,j,h] = sum_i e[b,j,i]*enc[b,i,h]
// d_out = [c (B*TD*H)] ++ [e (B*TD*TE)]
//
// Identity (R3): tanh(x) = 1 - 2/(1+exp2(Kx)); exp2(K(w+u)) = w~*u~ in the
// exp2 domain -> v_rcp is the only transcendental.
// R8: 4-way reciprocal batching (14 full-rate + 1 rcp per 4 elements).
// R9: pack fp32 math across j-pairs via <2 x float> (v_pk_fma_f32 on CDNA4):
// Uhe stored j-interleaved (Uhe4[j/4][h][4]) so one uniform dwordx4 load
// yields u for 4 j at one h; phase B packed the same way.
// Keeps: XCD swizzle (b=blockIdx&7), 4 j/block, interleaved W4 layout.
// R5 lesson: no (1024,8) launch bounds — spills (280 MB scratch traffic).

#define BB 8
#define TE 512
#define TD 256
#define HH 256

#define EXP2F(x) __builtin_amdgcn_exp2f(x)
#define RCPF(x)  __builtin_amdgcn_rcpf(x)
#define KSCALE   2.8853900817779268f    // 2*log2(e)
#define NSC      (-2.8853900817779268f) // -2*log2(e)

typedef float v2f __attribute__((ext_vector_type(2)));

// ---------------------------------------------------------------------------
// k_pre: C = [enc;dec] @ [Wa|Ua]; store exp2(KSCALE*C).
// Blocks 0..255: enc -> W4[b][h/4][i][4] (interleaved-transposed).
// Blocks 256..383: dec -> Uhe4[j/4][h][4] (j-interleaved).
// 64x64 tile, Kc=32, 4x4 per thread (tx=col-quad, ty=row-quad).
// ---------------------------------------------------------------------------
__global__ __launch_bounds__(256) void k_pre(
    const float* __restrict__ enc, const float* __restrict__ dec,
    const float* __restrict__ Wa,  const float* __restrict__ Ua,
    float* __restrict__ W4, float* __restrict__ Uhe4)
{
    const int tid = threadIdx.x;
    const bool is_enc = blockIdx.x < 256;
    const int bi = is_enc ? blockIdx.x : (blockIdx.x - 256);
    const int m0 = (bi >> 2) * 64;
    const int n0 = (bi & 3) * 64;
    const float* X = is_enc ? enc : dec;
    const float* W = is_enc ? Wa : Ua;

    __shared__ float Xs[32][68];
    __shared__ float Ws[32][68];

    const int kq = tid & 7,  xr = tid >> 3;
    const int wk = tid >> 3, wn = (tid & 7) * 8;
    const int tx = tid & 15, ty = tid >> 4;

    float acc[4][4];   // acc[r = row-offset][c = col-offset]
    #pragma unroll
    for (int r = 0; r < 4; r++)
        #pragma unroll
        for (int c = 0; c < 4; c++) acc[r][c] = 0.f;

    for (int kc = 0; kc < HH; kc += 32) {
        float4 xa = *(const float4*)(X + (size_t)(m0 + xr) * HH + kc + kq * 4);
        float4 xb = *(const float4*)(X + (size_t)(m0 + xr + 32) * HH + kc + kq * 4);
        float4 wa = *(const float4*)(W + (size_t)(kc + wk) * HH + n0 + wn);
        float4 wb = *(const float4*)(W + (size_t)(kc + wk) * HH + n0 + wn + 4);
        __syncthreads();
        Xs[kq * 4 + 0][xr] = xa.x; Xs[kq * 4 + 1][xr] = xa.y;
        Xs[kq * 4 + 2][xr] = xa.z; Xs[kq * 4 + 3][xr] = xa.w;
        Xs[kq * 4 + 0][xr + 32] = xb.x; Xs[kq * 4 + 1][xr + 32] = xb.y;
        Xs[kq * 4 + 2][xr + 32] = xb.z; Xs[kq * 4 + 3][xr + 32] = xb.w;
        *(float4*)&Ws[wk][wn]     = wa;
        *(float4*)&Ws[wk][wn + 4] = wb;
        __syncthreads();
        #pragma unroll
        for (int k = 0; k < 32; k++) {
            float4 a = *(const float4*)&Xs[k][ty * 4];   // 4 rows
            float4 b = *(const float4*)&Ws[k][tx * 4];   // 4 cols
            acc[0][0] = fmaf(a.x, b.x, acc[0][0]); acc[0][1] = fmaf(a.x, b.y, acc[0][1]);
            acc[0][2] = fmaf(a.x, b.z, acc[0][2]); acc[0][3] = fmaf(a.x, b.w, acc[0][3]);
            acc[1][0] = fmaf(a.y, b.x, acc[1][0]); acc[1][1] = fmaf(a.y, b.y, acc[1][1]);
            acc[1][2] = fmaf(a.y, b.z, acc[1][2]); acc[1][3] = fmaf(a.y, b.w, acc[1][3]);
            acc[2][0] = fmaf(a.z, b.x, acc[2][0]); acc[2][1] = fmaf(a.z, b.y, acc[2][1]);
            acc[2][2] = fmaf(a.z, b.z, acc[2][2]); acc[2][3] = fmaf(a.z, b.w, acc[2][3]);
            acc[3][0] = fmaf(a.w, b.x, acc[3][0]); acc[3][1] = fmaf(a.w, b.y, acc[3][1]);
            acc[3][2] = fmaf(a.w, b.z, acc[3][2]); acc[3][3] = fmaf(a.w, b.w, acc[3][3]);
        }
    }

    if (is_enc) {
        const int b  = m0 >> 9;                  // 512 enc rows per batch
        const int ib = (m0 & 511) + ty * 4;      // i base
        const int hq = (n0 >> 2) + tx;           // h-quad
        float* dst = W4 + (((size_t)b * 64 + hq) * TE + ib) * 4;
        #pragma unroll
        for (int r = 0; r < 4; r++) {
            float4 v;
            v.x = EXP2F(acc[r][0] * KSCALE); v.y = EXP2F(acc[r][1] * KSCALE);
            v.z = EXP2F(acc[r][2] * KSCALE); v.w = EXP2F(acc[r][3] * KSCALE);
            *(float4*)(dst + (size_t)r * 4) = v;
        }
    } else {
        // j-interleaved: Uhe4[(jj>>2)][h][jj&3]; rows m0+ty*4+r (r=jj&3)
        const int qd = (m0 + ty * 4) >> 2;       // aligned j-quad
        #pragma unroll
        for (int c = 0; c < 4; c++) {
            float4 v;
            v.x = EXP2F(acc[0][c] * KSCALE); v.y = EXP2F(acc[1][c] * KSCALE);
            v.z = EXP2F(acc[2][c] * KSCALE); v.w = EXP2F(acc[3][c] * KSCALE);
            *(float4*)(Uhe4 + ((size_t)qd * HH + n0 + tx * 4 + c) * 4) = v;
        }
    }
}

// ---------------------------------------------------------------------------
// 4-way batched reciprocal, packed over a j-pair:
//   sum_{t=0..3} v_t/A_t = (nAB*dCD + nCD*dAB)/(dAB*dCD), A_t = 1 + w_t*u_t
// All lanes of the v2f carry two different j's. 16 pk ops + 2 rcp / 8 elems.
// ---------------------------------------------------------------------------
__device__ __forceinline__ v2f qstep2(const float4& w4, const float4& v4,
                                      v2f u0, v2f u1, v2f u2, v2f u3, v2f acc)
{
    const v2f one = {1.f, 1.f};
    v2f A = __builtin_elementwise_fma((v2f)(w4.x), u0, one);
    v2f B = __builtin_elementwise_fma((v2f)(w4.y), u1, one);
    v2f C = __builtin_elementwise_fma((v2f)(w4.z), u2, one);
    v2f D = __builtin_elementwise_fma((v2f)(w4.w), u3, one);
    v2f dAB = A * B, dCD = C * D;
    v2f nAB = __builtin_elementwise_fma((v2f)(v4.x), B, (v2f)(v4.y) * A);
    v2f nCD = __builtin_elementwise_fma((v2f)(v4.z), D, (v2f)(v4.w) * C);
    v2f num = __builtin_elementwise_fma(nAB, dCD, nCD * dAB);
    v2f den = dAB * dCD;
    v2f r; r.x = RCPF(den.x); r.y = RCPF(den.y);
    return __builtin_elementwise_fma(num, r, acc);
}

// ---------------------------------------------------------------------------
// k_attn: 512 threads = 8 waves; block owns 4 consecutive j's of ONE batch,
// batch = blockIdx&7 (XCD-local). Phase A: wave w -> i = 64w+lane, 64 h-quads;
// per quad: one b128 W4 load (lane-varying) + 4 uniform j-interleaved u loads
// + uniform va load; packed math over 2 j-pairs. Softmax: waves 0-3.
// Phase B: wave w -> i in [64w,64w+64), all 4 j, packed; 32 KB LDS reduce.
// ---------------------------------------------------------------------------
__global__ __launch_bounds__(512) void k_attn(
    const float* __restrict__ enc, const float* __restrict__ W4,
    const float* __restrict__ Uhe4, const float* __restrict__ Va,
    float* __restrict__ out_c, float* __restrict__ out_e)
{
    const int wv = threadIdx.x >> 6, lane = threadIdx.x & 63;
    const int b   = blockIdx.x & 7;           // XCD-local batch
    const int j0  = (blockIdx.x >> 3) * 4;    // 64 j-groups per batch
    const int jj0 = b * TD + j0;              // block-uniform

    __shared__ float sP[TE][4];      // 8 KB: energies -> probabilities
    __shared__ float sR[8][4][HH];   // 32 KB: phase-B partials

    const int i = (wv << 6) + lane;
    const float* wp = W4 + ((size_t)b * 64 * TE + i) * 4;
    const float4* up = (const float4*)(Uhe4 + (size_t)(jj0 >> 2) * HH * 4);
    const float4* vp = (const float4*)Va;

    v2f a01 = {0.f, 0.f}, a23 = {0.f, 0.f};

    #pragma unroll 2
    for (int q = 0; q < 64; q++) {
        float4 w4 = *(const float4*)(wp + (size_t)q * TE * 4);
        float4 v4 = vp[q];                 // uniform
        float4 uh0 = up[4 * q + 0];        // uniform, {j0,j1,j2,j3} at h=4q
        float4 uh1 = up[4 * q + 1];
        float4 uh2 = up[4 * q + 2];
        float4 uh3 = up[4 * q + 3];
        v2f u0p, u1p, u2p, u3p;
        u0p.x = uh0.x; u0p.y = uh0.y; u1p.x = uh1.x; u1p.y = uh1.y;
        u2p.x = uh2.x; u2p.y = uh2.y; u3p.x = uh3.x; u3p.y = uh3.y;
        a01 = qstep2(w4, v4, u0p, u1p, u2p, u3p, a01);
        u0p.x = uh0.z; u0p.y = uh0.w; u1p.x = uh1.z; u1p.y = uh1.w;
        u2p.x = uh2.z; u2p.y = uh2.w; u3p.x = uh3.z; u3p.y = uh3.w;
        a23 = qstep2(w4, v4, u0p, u1p, u2p, u3p, a23);
    }

    // energies (log2 domain), j-interleaved row per i
    float4 E;
    E.x = NSC * a01.x; E.y = NSC * a01.y; E.z = NSC * a23.x; E.w = NSC * a23.y;
    *(float4*)&sP[i][0] = E;
    __syncthreads();

    // ---- softmax: wave w in 0..3 handles j0+w ----------------------------
    if (wv < 4) {
        float ev[8];
        float m = -3.0e38f;
        #pragma unroll
        for (int k = 0; k < 8; k++) {
            ev[k] = sP[lane + 64 * k][wv];
            m = fmaxf(m, ev[k]);
        }
        #pragma unroll
        for (int off = 32; off; off >>= 1) m = fmaxf(m, __shfl_xor(m, off, 64));
        float s = 0.f;
        #pragma unroll
        for (int k = 0; k < 8; k++) { ev[k] = EXP2F(ev[k] - m); s += ev[k]; }
        #pragma unroll
        for (int off = 32; off; off >>= 1) s += __shfl_xor(s, off, 64);
        float rs = RCPF(s);
        float* oe = out_e + (size_t)(jj0 + wv) * TE;
        #pragma unroll
        for (int k = 0; k < 8; k++) {
            float p = ev[k] * rs;
            sP[lane + 64 * k][wv] = p;
            oe[lane + 64 * k] = p;
        }
    }
    __syncthreads();

    // ---- Phase B: wave w -> i in [64w, 64w+64), all 4 j, packed over j ---
    const int ib = wv << 6;
    const float* eb = enc + ((size_t)b * TE + ib) * HH + 4 * lane;
    v2f cx01 = {0,0}, cy01 = {0,0}, cz01 = {0,0}, cw01 = {0,0};
    v2f cx23 = {0,0}, cy23 = {0,0}, cz23 = {0,0}, cw23 = {0,0};
    #pragma unroll 2
    for (int k = 0; k < 64; k++) {
        float4 p4 = *(const float4*)&sP[ib + k][0];   // uniform broadcast
        v2f p01; p01.x = p4.x; p01.y = p4.y;
        v2f p23; p23.x = p4.z; p23.y = p4.w;
        float4 q = *(const float4*)(eb + (size_t)k * HH);
        cx01 = __builtin_elementwise_fma(p01, (v2f)(q.x), cx01);
        cy01 = __builtin_elementwise_fma(p01, (v2f)(q.y), cy01);
        cz01 = __builtin_elementwise_fma(p01, (v2f)(q.z), cz01);
        cw01 = __builtin_elementwise_fma(p01, (v2f)(q.w), cw01);
        cx23 = __builtin_elementwise_fma(p23, (v2f)(q.x), cx23);
        cy23 = __builtin_elementwise_fma(p23, (v2f)(q.y), cy23);
        cz23 = __builtin_elementwise_fma(p23, (v2f)(q.z), cz23);
        cw23 = __builtin_elementwise_fma(p23, (v2f)(q.w), cw23);
    }
    {
        float4 c0, c1, c2, c3;
        c0.x = cx01.x; c0.y = cy01.x; c0.z = cz01.x; c0.w = cw01.x;
        c1.x = cx01.y; c1.y = cy01.y; c1.z = cz01.y; c1.w = cw01.y;
        c2.x = cx23.x; c2.y = cy23.x; c2.z = cz23.x; c2.w = cw23.x;
        c3.x = cx23.y; c3.y = cy23.y; c3.z = cz23.y; c3.w = cw23.y;
        *(float4*)&sR[wv][0][4 * lane] = c0;
        *(float4*)&sR[wv][1][4 * lane] = c1;
        *(float4*)&sR[wv][2][4 * lane] = c2;
        *(float4*)&sR[wv][3][4 * lane] = c3;
    }
    __syncthreads();

    // ---- final reduce: wave w -> (j = w&3, h-half = w>>2) ----------------
    {
        const int jr = wv & 3;
        const int h2 = (wv >> 2) * 128 + 2 * lane;
        float sx = 0.f, sy = 0.f;
        #pragma unroll
        for (int ww = 0; ww < 8; ww++) {
            float2 t = *(const float2*)&sR[ww][jr][h2];
            sx += t.x; sy += t.y;
        }
        float2 o; o.x = sx; o.y = sy;
        *(float2*)(out_c + (size_t)(jj0 + jr) * HH + h2) = o;
    }
}

extern "C" void kernel_launch(void* const* d_in, const int* in_sizes, int n_in,
                              void* d_out, int out_size, void* d_ws, size_t ws_size,
                              hipStream_t stream) {
    const float* enc = (const float*)d_in[0];
    const float* dec = (const float*)d_in[1];
    const float* Wa  = (const float*)d_in[2];
    const float* Ua  = (const float*)d_in[3];
    const float* Va  = (const float*)d_in[4];

    float* W4   = (float*)d_ws;                      // exp2-domain, i-interleaved
    float* Uhe4 = W4 + (size_t)BB * HH * TE;         // exp2-domain, j-interleaved

    float* out_c = (float*)d_out;                    // [B,TD,H]
    float* out_e = out_c + (size_t)BB * TD * HH;     // [B,TD,TE]

    k_pre<<<384, 256, 0, stream>>>(enc, dec, Wa, Ua, W4, Uhe4);
    k_attn<<<BB * TD / 4, 512, 0, stream>>>(enc, W4, Uhe4, Va, out_c, out_e);
}